// Round 13
// baseline (70.043 us; speedup 1.0000x reference)
//
#include <hip/hip_runtime.h>
#include <hip/hip_bf16.h>

#define SDIM 4096
#define DDIM 64
#define HN   16
#define BH   64
#define NC   16

typedef __attribute__((ext_vector_type(8))) short short8;
typedef __attribute__((ext_vector_type(4))) float f32x4;

static __device__ __forceinline__ unsigned f2bfu(float f) {
    __hip_bfloat16 h = __float2bfloat16(f);
    return (unsigned)*reinterpret_cast<unsigned short*>(&h);
}
static __device__ __forceinline__ short f2bfs(float f) {
    __hip_bfloat16 h = __float2bfloat16(f);
    return *reinterpret_cast<short*>(&h);
}

#define SPITCH 72   // bytes per d-row (32 bf16 s + 8 pad): b64 reads conflict-free

// ---------------------------------------------------------------------------
// k1 v10: per (bh, 256-row chunk) partial KV[64][64] + ksum[64].
//  ZERO barriers in the K-loop (k3's proven regime). Each wave owns 64 rows:
//   - dwordx4 granule loads (16 rows), 2-deep ping-pong prefetch;
//   - relu+mask+cvt once in regs, shfl-pair bf16 pack (v9-validated) into a
//     WAVE-PRIVATE transposed strip [64 d][72 B] (in-order DS pipe -> no
//     sync needed; pitch 72 -> conflict-free ds_read_b64 fragments);
//   - 16 MFMA (16x16x32) per 32-s step, acc[4][4] full 64x64 per wave.
//  Issue-rate math: dword gathers = 55us wall (r6/v8 measured); dwordx4 =
//  ~14us. Epilogue: cross-wave reduce via 4 dt-passes of 16KB LDS strips.
// ---------------------------------------------------------------------------
__global__ __launch_bounds__(256, 3) void k1_kv(
    const float* __restrict__ K, const float* __restrict__ V,
    const int* __restrict__ mask,
    float* __restrict__ KVp, float* __restrict__ ksump)
{
    __shared__ __align__(16) char smem[36864];
    const int tid = threadIdx.x;
    const int w = tid >> 6, l = tid & 63;
    const int a = l & 15, quad = l >> 4;
    const int bh = blockIdx.x >> 4, ch = blockIdx.x & 15;
    const int b  = bh >> 4;                 // bh / HN
    const long base = (long)bh * SDIM * DDIM;
    const int s0 = ch * 256 + w * 64;       // wave's private 64 s-rows

    char* const KT = smem + w * 9216;       // [64][72]
    char* const VT = smem + w * 9216 + 4608;
    const int par = quad & 1;
    const int c4  = a << 2;

    f32x4 acc[4][4];
#pragma unroll
    for (int i = 0; i < 4; ++i)
#pragma unroll
        for (int j = 0; j < 4; ++j) acc[i][j] = (f32x4){0.f, 0.f, 0.f, 0.f};
    float ks4[4] = {0.f, 0.f, 0.f, 0.f};

    auto LOADG = [&](int g, f32x4* kr, f32x4* vr, float* mr) {
#pragma unroll
        for (int gg = 0; gg < 4; ++gg) {
            const int row = s0 + g * 16 + gg * 4 + quad;
            kr[gg] = *(const f32x4*)(K + base + (long)row * DDIM + c4);
            vr[gg] = *(const f32x4*)(V + base + (long)row * DDIM + c4);
            mr[gg] = mask[b * SDIM + row] ? 1.f : 0.f;
        }
    };
    auto PACKG = [&](int g, f32x4* kr, f32x4* vr, float* mr) {
#pragma unroll
        for (int gg = 0; gg < 4; ++gg) {
            float kq[4];
#pragma unroll
            for (int j = 0; j < 4; ++j) {
                kq[j] = fmaxf(kr[gg][j], 0.f) * mr[gg];
                ks4[j] += kq[j];
            }
            unsigned ku[4], vu[4];
#pragma unroll
            for (int j = 0; j < 4; ++j) {
                ku[j] = f2bfu(kq[j]);
                vu[j] = f2bfu(vr[gg][j]);
            }
            const int sp = (g & 1) * 8 + gg * 2 + (quad >> 1);
            const int j0 = par * 2;
            unsigned kp[4], vp[4];
#pragma unroll
            for (int j = 0; j < 4; ++j) {
                const unsigned pk = (unsigned)__shfl_xor((int)ku[j], 16);
                const unsigned pv = (unsigned)__shfl_xor((int)vu[j], 16);
                kp[j] = par ? (pk | (ku[j] << 16)) : (ku[j] | (pk << 16));
                vp[j] = par ? (pv | (vu[j] << 16)) : (vu[j] | (pv << 16));
            }
            *(unsigned*)(KT + (c4 + j0)     * SPITCH + sp * 4) = kp[j0];
            *(unsigned*)(KT + (c4 + j0 + 1) * SPITCH + sp * 4) = kp[j0 + 1];
            *(unsigned*)(VT + (c4 + j0)     * SPITCH + sp * 4) = vp[j0];
            *(unsigned*)(VT + (c4 + j0 + 1) * SPITCH + sp * 4) = vp[j0 + 1];
        }
    };
    auto COMPUTE = [&]() {
        short8 af[4], bf[4];
#pragma unroll
        for (int dt = 0; dt < 4; ++dt) {
            const char* rp = KT + (dt * 16 + a) * SPITCH + quad * 16;
            const uint2 lo = *(const uint2*)rp;
            const uint2 hi = *(const uint2*)(rp + 8);
            int4 ra; ra.x = lo.x; ra.y = lo.y; ra.z = hi.x; ra.w = hi.y;
            af[dt] = *(short8*)&ra;
            const char* vpn = VT + (dt * 16 + a) * SPITCH + quad * 16;
            const uint2 vlo = *(const uint2*)vpn;
            const uint2 vhi = *(const uint2*)(vpn + 8);
            int4 rb; rb.x = vlo.x; rb.y = vlo.y; rb.z = vhi.x; rb.w = vhi.y;
            bf[dt] = *(short8*)&rb;
        }
#pragma unroll
        for (int dt = 0; dt < 4; ++dt)
#pragma unroll
            for (int et = 0; et < 4; ++et)
                acc[dt][et] = __builtin_amdgcn_mfma_f32_16x16x32_bf16(
                    af[dt], bf[et], acc[dt][et], 0, 0, 0);
    };

    f32x4 kA[4], vA[4], kB[4], vB[4];
    float mA[4], mB[4];
    LOADG(0, kA, vA, mA);                  // 2-deep ping-pong prefetch
    LOADG(1, kB, vB, mB);
    PACKG(0, kA, vA, mA);
    LOADG(2, kA, vA, mA);
    PACKG(1, kB, vB, mB);
    LOADG(3, kB, vB, mB);
    COMPUTE();                              // step 0 (granules 0,1)
    PACKG(2, kA, vA, mA);
    PACKG(3, kB, vB, mB);
    COMPUTE();                              // step 1 (granules 2,3)

    // ---- ksum wave-reduce: lanes l, l^16, l^32, l^48 share d-cols ----
#pragma unroll
    for (int j = 0; j < 4; ++j) {
        ks4[j] += __shfl_xor(ks4[j], 16);
        ks4[j] += __shfl_xor(ks4[j], 32);
    }
    __syncthreads();                        // all staging reads done
    float* const kswork = (float*)(smem + 16384);   // 1 KB
    if (l < 16) {
#pragma unroll
        for (int j = 0; j < 4; ++j) kswork[w * 64 + l * 4 + j] = ks4[j];
    }

    // ---- KV cross-wave reduce: 4 dt-passes through 16 KB strips ----
    float* const strip = (float*)smem;      // [4][1024]
    float* outp = KVp + ((long)bh * NC + ch) * 4096;
#pragma unroll
    for (int dt = 0; dt < 4; ++dt) {
        __syncthreads();
#pragma unroll
        for (int et = 0; et < 4; ++et)
#pragma unroll
            for (int r = 0; r < 4; ++r)
                strip[w * 1024 + (quad * 4 + r) * 64 + et * 16 + a] =
                    acc[dt][et][r];
        __syncthreads();
#pragma unroll
        for (int i = 0; i < 4; ++i) {
            const int idx = i * 256 + tid;
            outp[dt * 1024 + idx] = strip[idx] + strip[1024 + idx] +
                                    strip[2048 + idx] + strip[3072 + idx];
        }
    }
    if (tid < 64)
        ksump[((long)bh * NC + ch) * 64 + tid] =
            kswork[tid] + kswork[64 + tid] + kswork[128 + tid] + kswork[192 + tid];
}

// ---------------------------------------------------------------------------
// k2: reduce NC chunk partials -> final KV, ksum. (unchanged, validated)
// ---------------------------------------------------------------------------
__global__ __launch_bounds__(256) void k2_reduce(
    const float* __restrict__ KVp, const float* __restrict__ ksump,
    float* __restrict__ KV, float* __restrict__ ksum)
{
    const int bh = blockIdx.x >> 2;
    const int qt = blockIdx.x & 3;
    const int tid = threadIdx.x;
#pragma unroll
    for (int i = 0; i < 4; ++i) {
        const int idx = qt * 1024 + i * 256 + tid;
        float v = 0.f;
#pragma unroll
        for (int c = 0; c < NC; ++c) v += KVp[((long)bh * NC + c) * 4096 + idx];
        KV[(long)bh * 4096 + idx] = v;
    }
    if (qt == 0 && tid < 64) {
        float v = 0.f;
#pragma unroll
        for (int c = 0; c < NC; ++c) v += ksump[((long)bh * NC + c) * 64 + tid];
        ksum[bh * 64 + tid] = v;
    }
}

// ---------------------------------------------------------------------------
// k3 v4 (MFMA): out = (relu(Q) @ KV_bf16) * (1/norm), norm fp32.
// (unchanged, validated)
// ---------------------------------------------------------------------------
__global__ __launch_bounds__(256, 4) void k3_out(
    const float* __restrict__ Q, const float* __restrict__ KVm,
    const float* __restrict__ ksum, float* __restrict__ out)
{
    __shared__ float cbuf[4][16 * 68];     // 17.4 KB, per-wave strips
    const int tid  = threadIdx.x;
    const int w    = tid >> 6;
    const int l    = tid & 63;
    const int r16  = l & 15;
    const int quad = l >> 4;
    const int bh    = blockIdx.x >> 4;
    const int strip = blockIdx.x & 15;     // 16 strips x 256 rows

    const float* kvp = KVm + (long)bh * 4096;
    short8 bfrag[2][4];
#pragma unroll
    for (int kh = 0; kh < 2; ++kh)
#pragma unroll
        for (int n = 0; n < 4; ++n) {
            short8 tmp;
#pragma unroll
            for (int j = 0; j < 8; ++j)
                tmp[j] = f2bfs(kvp[(kh * 32 + quad * 8 + j) * 64 + n * 16 + r16]);
            bfrag[kh][n] = tmp;
        }
    float ksv[16];
#pragma unroll
    for (int j = 0; j < 8; ++j) {
        ksv[j]     = ksum[bh * 64 + quad * 8 + j];
        ksv[j + 8] = ksum[bh * 64 + 32 + quad * 8 + j];
    }

    const int rowbase = strip * 256 + w * 64;
    const float* qptr = Q + ((long)bh * SDIM + rowbase + r16) * DDIM + quad * 8;
    float* obase = out + ((long)bh * SDIM + rowbase) * DDIM;
    float* cw = &cbuf[w][0];

    f32x4 a0 = *(const f32x4*)(qptr);
    f32x4 a1 = *(const f32x4*)(qptr + 4);
    f32x4 a2 = *(const f32x4*)(qptr + 32);
    f32x4 a3 = *(const f32x4*)(qptr + 36);

    for (int t = 0; t < 4; ++t) {
        f32x4 b0 = a0, b1 = a1, b2 = a2, b3 = a3;
        if (t < 3) {
            const float* qn = qptr + (t + 1) * 16 * DDIM;
            b0 = *(const f32x4*)(qn);
            b1 = *(const f32x4*)(qn + 4);
            b2 = *(const f32x4*)(qn + 32);
            b3 = *(const f32x4*)(qn + 36);
        }
#pragma unroll
        for (int j = 0; j < 4; ++j) {
            a0[j] = fmaxf(a0[j], 0.f); a1[j] = fmaxf(a1[j], 0.f);
            a2[j] = fmaxf(a2[j], 0.f); a3[j] = fmaxf(a3[j], 0.f);
        }
        float p = 0.f;
#pragma unroll
        for (int j = 0; j < 4; ++j) {
            p = fmaf(a0[j], ksv[j],      p);
            p = fmaf(a1[j], ksv[4 + j],  p);
            p = fmaf(a2[j], ksv[8 + j],  p);
            p = fmaf(a3[j], ksv[12 + j], p);
        }
        p += __shfl_xor(p, 16);
        p += __shfl_xor(p, 32);
        const float inv = __builtin_amdgcn_rcpf(p);

        short8 af0, af1;
#pragma unroll
        for (int j = 0; j < 4; ++j) {
            af0[j]     = f2bfs(a0[j]);
            af0[4 + j] = f2bfs(a1[j]);
            af1[j]     = f2bfs(a2[j]);
            af1[4 + j] = f2bfs(a3[j]);
        }

        f32x4 acc[4];
#pragma unroll
        for (int n = 0; n < 4; ++n) {
            acc[n] = (f32x4){0.f, 0.f, 0.f, 0.f};
            acc[n] = __builtin_amdgcn_mfma_f32_16x16x32_bf16(af0, bfrag[0][n], acc[n], 0, 0, 0);
            acc[n] = __builtin_amdgcn_mfma_f32_16x16x32_bf16(af1, bfrag[1][n], acc[n], 0, 0, 0);
        }

        float invr[4];
#pragma unroll
        for (int r = 0; r < 4; ++r) invr[r] = __shfl(inv, quad * 4 + r);

#pragma unroll
        for (int n = 0; n < 4; ++n)
#pragma unroll
            for (int r = 0; r < 4; ++r)
                cw[(quad * 4 + r) * 68 + n * 16 + r16] = acc[n][r] * invr[r];

        float* ot = obase + (t * 16) * DDIM;
#pragma unroll
        for (int i = 0; i < 4; ++i) {
            f32x4 v = *(const f32x4*)(cw + (i * 4 + quad) * 68 + r16 * 4);
            *(f32x4*)(ot + (i * 4 + quad) * DDIM + r16 * 4) = v;
        }
        a0 = b0; a1 = b1; a2 = b2; a3 = b3;
    }
}

extern "C" void kernel_launch(void* const* d_in, const int* in_sizes, int n_in,
                              void* d_out, int out_size, void* d_ws, size_t ws_size,
                              hipStream_t stream)
{
    const float* Q    = (const float*)d_in[0];
    const float* K    = (const float*)d_in[1];
    const float* V    = (const float*)d_in[2];
    const int*   mask = (const int*)d_in[3];
    float* out = (float*)d_out;

    // Chunk partials live in d_out (scratch; k3 overwrites all of d_out).
    float* KVp   = out;                                // 16.8 MB scratch
    float* ksump = KVp + (long)BH * NC * 4096;         // 256 KB
    float* KV    = (float*)d_ws;                       // 1 MB
    float* ksum  = KV + (long)BH * 4096;               // 16 KB

    hipLaunchKernelGGL(k1_kv, dim3(BH * NC), dim3(256), 0, stream,
                       K, V, mask, KVp, ksump);
    hipLaunchKernelGGL(k2_reduce, dim3(BH * 4), dim3(256), 0, stream,
                       KVp, ksump, KV, ksum);
    hipLaunchKernelGGL(k3_out, dim3(BH * 16), dim3(256), 0, stream,
                       Q, KV, ksum, out);
}

// Round 14
// 62.877 us; speedup vs baseline: 1.1140x; 1.1140x over previous
//
#include <hip/hip_runtime.h>
#include <hip/hip_bf16.h>

#define SDIM 4096
#define DDIM 64
#define HN   16
#define BH   64
#define NC   16

typedef __attribute__((ext_vector_type(8))) short short8;
typedef __attribute__((ext_vector_type(4))) float f32x4;

static __device__ __forceinline__ unsigned f2bfu(float f) {
    __hip_bfloat16 h = __float2bfloat16(f);
    return (unsigned)*reinterpret_cast<unsigned short*>(&h);
}
static __device__ __forceinline__ short f2bfs(float f) {
    __hip_bfloat16 h = __float2bfloat16(f);
    return *reinterpret_cast<short*>(&h);
}

#define SPITCH 72   // bytes per d-row (32 bf16 s + 8 pad): b64 reads conflict-free

// ---------------------------------------------------------------------------
// k1 v10: per (bh, 256-row chunk) partial KV[64][64] + ksum[64].
// (unchanged from round 13 — known-pass at 54 us; this round's single
//  variable is k3's non-temporal output stores, which should leave K/V
//  L3-resident across replays and collapse k1's HBM fetch.)
// ---------------------------------------------------------------------------
__global__ __launch_bounds__(256, 3) void k1_kv(
    const float* __restrict__ K, const float* __restrict__ V,
    const int* __restrict__ mask,
    float* __restrict__ KVp, float* __restrict__ ksump)
{
    __shared__ __align__(16) char smem[36864];
    const int tid = threadIdx.x;
    const int w = tid >> 6, l = tid & 63;
    const int a = l & 15, quad = l >> 4;
    const int bh = blockIdx.x >> 4, ch = blockIdx.x & 15;
    const int b  = bh >> 4;                 // bh / HN
    const long base = (long)bh * SDIM * DDIM;
    const int s0 = ch * 256 + w * 64;       // wave's private 64 s-rows

    char* const KT = smem + w * 9216;       // [64][72]
    char* const VT = smem + w * 9216 + 4608;
    const int par = quad & 1;
    const int c4  = a << 2;

    f32x4 acc[4][4];
#pragma unroll
    for (int i = 0; i < 4; ++i)
#pragma unroll
        for (int j = 0; j < 4; ++j) acc[i][j] = (f32x4){0.f, 0.f, 0.f, 0.f};
    float ks4[4] = {0.f, 0.f, 0.f, 0.f};

    auto LOADG = [&](int g, f32x4* kr, f32x4* vr, float* mr) {
#pragma unroll
        for (int gg = 0; gg < 4; ++gg) {
            const int row = s0 + g * 16 + gg * 4 + quad;
            kr[gg] = *(const f32x4*)(K + base + (long)row * DDIM + c4);
            vr[gg] = *(const f32x4*)(V + base + (long)row * DDIM + c4);
            mr[gg] = mask[b * SDIM + row] ? 1.f : 0.f;
        }
    };
    auto PACKG = [&](int g, f32x4* kr, f32x4* vr, float* mr) {
#pragma unroll
        for (int gg = 0; gg < 4; ++gg) {
            float kq[4];
#pragma unroll
            for (int j = 0; j < 4; ++j) {
                kq[j] = fmaxf(kr[gg][j], 0.f) * mr[gg];
                ks4[j] += kq[j];
            }
            unsigned ku[4], vu[4];
#pragma unroll
            for (int j = 0; j < 4; ++j) {
                ku[j] = f2bfu(kq[j]);
                vu[j] = f2bfu(vr[gg][j]);
            }
            const int sp = (g & 1) * 8 + gg * 2 + (quad >> 1);
            const int j0 = par * 2;
            unsigned kp[4], vp[4];
#pragma unroll
            for (int j = 0; j < 4; ++j) {
                const unsigned pk = (unsigned)__shfl_xor((int)ku[j], 16);
                const unsigned pv = (unsigned)__shfl_xor((int)vu[j], 16);
                kp[j] = par ? (pk | (ku[j] << 16)) : (ku[j] | (pk << 16));
                vp[j] = par ? (pv | (vu[j] << 16)) : (vu[j] | (pv << 16));
            }
            *(unsigned*)(KT + (c4 + j0)     * SPITCH + sp * 4) = kp[j0];
            *(unsigned*)(KT + (c4 + j0 + 1) * SPITCH + sp * 4) = kp[j0 + 1];
            *(unsigned*)(VT + (c4 + j0)     * SPITCH + sp * 4) = vp[j0];
            *(unsigned*)(VT + (c4 + j0 + 1) * SPITCH + sp * 4) = vp[j0 + 1];
        }
    };
    auto COMPUTE = [&]() {
        short8 af[4], bf[4];
#pragma unroll
        for (int dt = 0; dt < 4; ++dt) {
            const char* rp = KT + (dt * 16 + a) * SPITCH + quad * 16;
            const uint2 lo = *(const uint2*)rp;
            const uint2 hi = *(const uint2*)(rp + 8);
            int4 ra; ra.x = lo.x; ra.y = lo.y; ra.z = hi.x; ra.w = hi.y;
            af[dt] = *(short8*)&ra;
            const char* vpn = VT + (dt * 16 + a) * SPITCH + quad * 16;
            const uint2 vlo = *(const uint2*)vpn;
            const uint2 vhi = *(const uint2*)(vpn + 8);
            int4 rb; rb.x = vlo.x; rb.y = vlo.y; rb.z = vhi.x; rb.w = vhi.y;
            bf[dt] = *(short8*)&rb;
        }
#pragma unroll
        for (int dt = 0; dt < 4; ++dt)
#pragma unroll
            for (int et = 0; et < 4; ++et)
                acc[dt][et] = __builtin_amdgcn_mfma_f32_16x16x32_bf16(
                    af[dt], bf[et], acc[dt][et], 0, 0, 0);
    };

    f32x4 kA[4], vA[4], kB[4], vB[4];
    float mA[4], mB[4];
    LOADG(0, kA, vA, mA);                  // 2-deep ping-pong prefetch
    LOADG(1, kB, vB, mB);
    PACKG(0, kA, vA, mA);
    LOADG(2, kA, vA, mA);
    PACKG(1, kB, vB, mB);
    LOADG(3, kB, vB, mB);
    COMPUTE();                              // step 0 (granules 0,1)
    PACKG(2, kA, vA, mA);
    PACKG(3, kB, vB, mB);
    COMPUTE();                              // step 1 (granules 2,3)

    // ---- ksum wave-reduce ----
#pragma unroll
    for (int j = 0; j < 4; ++j) {
        ks4[j] += __shfl_xor(ks4[j], 16);
        ks4[j] += __shfl_xor(ks4[j], 32);
    }
    __syncthreads();                        // all staging reads done
    float* const kswork = (float*)(smem + 16384);   // 1 KB
    if (l < 16) {
#pragma unroll
        for (int j = 0; j < 4; ++j) kswork[w * 64 + l * 4 + j] = ks4[j];
    }

    // ---- KV cross-wave reduce: 4 dt-passes through 16 KB strips ----
    float* const strip = (float*)smem;      // [4][1024]
    float* outp = KVp + ((long)bh * NC + ch) * 4096;
#pragma unroll
    for (int dt = 0; dt < 4; ++dt) {
        __syncthreads();
#pragma unroll
        for (int et = 0; et < 4; ++et)
#pragma unroll
            for (int r = 0; r < 4; ++r)
                strip[w * 1024 + (quad * 4 + r) * 64 + et * 16 + a] =
                    acc[dt][et][r];
        __syncthreads();
#pragma unroll
        for (int i = 0; i < 4; ++i) {
            const int idx = i * 256 + tid;
            outp[dt * 1024 + idx] = strip[idx] + strip[1024 + idx] +
                                    strip[2048 + idx] + strip[3072 + idx];
        }
    }
    if (tid < 64)
        ksump[((long)bh * NC + ch) * 64 + tid] =
            kswork[tid] + kswork[64 + tid] + kswork[128 + tid] + kswork[192 + tid];
}

// ---------------------------------------------------------------------------
// k2: reduce NC chunk partials -> final KV, ksum. (unchanged, validated)
// ---------------------------------------------------------------------------
__global__ __launch_bounds__(256) void k2_reduce(
    const float* __restrict__ KVp, const float* __restrict__ ksump,
    float* __restrict__ KV, float* __restrict__ ksum)
{
    const int bh = blockIdx.x >> 2;
    const int qt = blockIdx.x & 3;
    const int tid = threadIdx.x;
#pragma unroll
    for (int i = 0; i < 4; ++i) {
        const int idx = qt * 1024 + i * 256 + tid;
        float v = 0.f;
#pragma unroll
        for (int c = 0; c < NC; ++c) v += KVp[((long)bh * NC + c) * 4096 + idx];
        KV[(long)bh * 4096 + idx] = v;
    }
    if (qt == 0 && tid < 64) {
        float v = 0.f;
#pragma unroll
        for (int c = 0; c < NC; ++c) v += ksump[((long)bh * NC + c) * 64 + tid];
        ksum[bh * 64 + tid] = v;
    }
}

// ---------------------------------------------------------------------------
// k3 v5: identical math to validated v4, but final output stores are
// NON-TEMPORAL (bypass L2/L3 retention) so the 67 MB out-churn stops
// evicting K/V from Infinity Cache between replays.
// ---------------------------------------------------------------------------
__global__ __launch_bounds__(256, 4) void k3_out(
    const float* __restrict__ Q, const float* __restrict__ KVm,
    const float* __restrict__ ksum, float* __restrict__ out)
{
    __shared__ float cbuf[4][16 * 68];     // 17.4 KB, per-wave strips
    const int tid  = threadIdx.x;
    const int w    = tid >> 6;
    const int l    = tid & 63;
    const int r16  = l & 15;
    const int quad = l >> 4;
    const int bh    = blockIdx.x >> 4;
    const int strip = blockIdx.x & 15;     // 16 strips x 256 rows

    const float* kvp = KVm + (long)bh * 4096;
    short8 bfrag[2][4];
#pragma unroll
    for (int kh = 0; kh < 2; ++kh)
#pragma unroll
        for (int n = 0; n < 4; ++n) {
            short8 tmp;
#pragma unroll
            for (int j = 0; j < 8; ++j)
                tmp[j] = f2bfs(kvp[(kh * 32 + quad * 8 + j) * 64 + n * 16 + r16]);
            bfrag[kh][n] = tmp;
        }
    float ksv[16];
#pragma unroll
    for (int j = 0; j < 8; ++j) {
        ksv[j]     = ksum[bh * 64 + quad * 8 + j];
        ksv[j + 8] = ksum[bh * 64 + 32 + quad * 8 + j];
    }

    const int rowbase = strip * 256 + w * 64;
    const float* qptr = Q + ((long)bh * SDIM + rowbase + r16) * DDIM + quad * 8;
    float* obase = out + ((long)bh * SDIM + rowbase) * DDIM;
    float* cw = &cbuf[w][0];

    f32x4 a0 = *(const f32x4*)(qptr);
    f32x4 a1 = *(const f32x4*)(qptr + 4);
    f32x4 a2 = *(const f32x4*)(qptr + 32);
    f32x4 a3 = *(const f32x4*)(qptr + 36);

    for (int t = 0; t < 4; ++t) {
        f32x4 b0 = a0, b1 = a1, b2 = a2, b3 = a3;
        if (t < 3) {
            const float* qn = qptr + (t + 1) * 16 * DDIM;
            b0 = *(const f32x4*)(qn);
            b1 = *(const f32x4*)(qn + 4);
            b2 = *(const f32x4*)(qn + 32);
            b3 = *(const f32x4*)(qn + 36);
        }
#pragma unroll
        for (int j = 0; j < 4; ++j) {
            a0[j] = fmaxf(a0[j], 0.f); a1[j] = fmaxf(a1[j], 0.f);
            a2[j] = fmaxf(a2[j], 0.f); a3[j] = fmaxf(a3[j], 0.f);
        }
        float p = 0.f;
#pragma unroll
        for (int j = 0; j < 4; ++j) {
            p = fmaf(a0[j], ksv[j],      p);
            p = fmaf(a1[j], ksv[4 + j],  p);
            p = fmaf(a2[j], ksv[8 + j],  p);
            p = fmaf(a3[j], ksv[12 + j], p);
        }
        p += __shfl_xor(p, 16);
        p += __shfl_xor(p, 32);
        const float inv = __builtin_amdgcn_rcpf(p);

        short8 af0, af1;
#pragma unroll
        for (int j = 0; j < 4; ++j) {
            af0[j]     = f2bfs(a0[j]);
            af0[4 + j] = f2bfs(a1[j]);
            af1[j]     = f2bfs(a2[j]);
            af1[4 + j] = f2bfs(a3[j]);
        }

        f32x4 acc[4];
#pragma unroll
        for (int n = 0; n < 4; ++n) {
            acc[n] = (f32x4){0.f, 0.f, 0.f, 0.f};
            acc[n] = __builtin_amdgcn_mfma_f32_16x16x32_bf16(af0, bfrag[0][n], acc[n], 0, 0, 0);
            acc[n] = __builtin_amdgcn_mfma_f32_16x16x32_bf16(af1, bfrag[1][n], acc[n], 0, 0, 0);
        }

        float invr[4];
#pragma unroll
        for (int r = 0; r < 4; ++r) invr[r] = __shfl(inv, quad * 4 + r);

#pragma unroll
        for (int n = 0; n < 4; ++n)
#pragma unroll
            for (int r = 0; r < 4; ++r)
                cw[(quad * 4 + r) * 68 + n * 16 + r16] = acc[n][r] * invr[r];

        float* ot = obase + (t * 16) * DDIM;
#pragma unroll
        for (int i = 0; i < 4; ++i) {
            f32x4 v = *(const f32x4*)(cw + (i * 4 + quad) * 68 + r16 * 4);
            __builtin_nontemporal_store(
                v, (f32x4*)(ot + (i * 4 + quad) * DDIM + r16 * 4));
        }
        a0 = b0; a1 = b1; a2 = b2; a3 = b3;
    }
}

extern "C" void kernel_launch(void* const* d_in, const int* in_sizes, int n_in,
                              void* d_out, int out_size, void* d_ws, size_t ws_size,
                              hipStream_t stream)
{
    const float* Q    = (const float*)d_in[0];
    const float* K    = (const float*)d_in[1];
    const float* V    = (const float*)d_in[2];
    const int*   mask = (const int*)d_in[3];
    float* out = (float*)d_out;

    // Chunk partials live in d_out (scratch; k3 overwrites all of d_out).
    float* KVp   = out;                                // 16.8 MB scratch
    float* ksump = KVp + (long)BH * NC * 4096;         // 256 KB
    float* KV    = (float*)d_ws;                       // 1 MB
    float* ksum  = KV + (long)BH * 4096;               // 16 KB

    hipLaunchKernelGGL(k1_kv, dim3(BH * NC), dim3(256), 0, stream,
                       K, V, mask, KVp, ksump);
    hipLaunchKernelGGL(k2_reduce, dim3(BH * 4), dim3(256), 0, stream,
                       KVp, ksump, KV, ksum);
    hipLaunchKernelGGL(k3_out, dim3(BH * 16), dim3(256), 0, stream,
                       Q, KV, ksum, out);
}